// Round 20
// baseline (177.584 us; speedup 1.0000x reference)
//
#include <hip/hip_runtime.h>

constexpr int Bn = 4, CG = 16, HH = 384, WW = 384;
constexpr int HWSZ = HH * WW;  // 147456
constexpr int COUT = 24;

// ---------------------------------------------------------------------------
// Weight transpose: Wt[(ic*9+t)*24 + oc] = Wc[(oc*16+ic)*9 + t]
// ---------------------------------------------------------------------------
__global__ void wtrans_kernel(const float* __restrict__ Wc,
                              float* __restrict__ Wt) {
  int i = blockIdx.x * 256 + threadIdx.x;
  if (i < COUT * CG * 9) {
    int oc = i / (CG * 9), rem = i % (CG * 9);
    Wt[rem * COUT + oc] = Wc[i];
  }
}

// ---------------------------------------------------------------------------
// Conv 3x3 SAME 16->24: 32x16 tile, 256 thr, 2 px/thread, 4-ic LDS quarters.
// NEW: weights staged in LDS (13.8 KB) and read via broadcast ds_read_b128.
// Rationale: s_load (weights) and ds_read (tile) share lgkmcnt with
// UNORDERED cross-type returns -> compiler emits lgkmcnt(0) per weight
// chunk, serializing the pipeline (VALUBusy stuck ~48% for 4 rounds).
// All-DS operand traffic has in-order returns -> incremental lgkmcnt(N).
// ---------------------------------------------------------------------------
__global__ __launch_bounds__(256) void conv4_kernel(
    const float* __restrict__ g, const float* __restrict__ Wt,
    const float* __restrict__ bc, float* __restrict__ out_off,
    float* __restrict__ affc) {
  __shared__ float wlds[144 * 24];    // 13.8 KB
  __shared__ float lds[4 * 18 * 34];  //  9.8 KB
  int bi = blockIdx.x;
  int bx = (bi % 12) * 32;
  int by = ((bi / 12) % 24) * 16;
  int b = bi / 288;
  const float* gb = g + (size_t)b * CG * HWSZ;

  int t = threadIdx.x;
  for (int k = t; k < 144 * 24; k += 256) wlds[k] = Wt[k];

  int tx = t & 15, ty = t >> 4;
  float acc0[COUT], acc1[COUT];
#pragma unroll
  for (int oc = 0; oc < COUT; ++oc) {
    float bv = bc[oc];
    acc0[oc] = bv;
    acc1[oc] = bv;
  }

  for (int quarter = 0; quarter < 4; ++quarter) {
    __syncthreads();  // lds reuse (and wlds ready before first compute)
    for (int k = t; k < 4 * 612; k += 256) {
      int icl = k / 612, rem = k - 612 * icl;
      int y = rem / 34, x = rem - 34 * y;
      int gy = by + y - 1, gx = bx + x - 1;
      float v = (gy >= 0 && gy < HH && gx >= 0 && gx < WW)
                    ? gb[(quarter * 4 + icl) * HWSZ + gy * WW + gx]
                    : 0.f;
      lds[k] = v;
    }
    __syncthreads();

    for (int icl = 0; icl < 4; ++icl) {
      int ic = quarter * 4 + icl;
      const float* base = lds + icl * 612 + ty * 34 + 2 * tx;
      float vals[3][4];
#pragma unroll
      for (int r = 0; r < 3; ++r) {
        float2 v01 = *(const float2*)(base + r * 34);
        float2 v23 = *(const float2*)(base + r * 34 + 2);
        vals[r][0] = v01.x;
        vals[r][1] = v01.y;
        vals[r][2] = v23.x;
        vals[r][3] = v23.y;
      }
#pragma unroll
      for (int r = 0; r < 3; ++r) {
#pragma unroll
        for (int c3 = 0; c3 < 3; ++c3) {
          float va = vals[r][c3], vb = vals[r][c3 + 1];
          const float* wp = &wlds[(ic * 9 + r * 3 + c3) * COUT];
          float4 w0 = *(const float4*)(wp + 0);
          float4 w1 = *(const float4*)(wp + 4);
          float4 w2 = *(const float4*)(wp + 8);
          float4 w3 = *(const float4*)(wp + 12);
          float4 w4 = *(const float4*)(wp + 16);
          float4 w5 = *(const float4*)(wp + 20);
          float wv[COUT] = {w0.x, w0.y, w0.z, w0.w, w1.x, w1.y, w1.z, w1.w,
                            w2.x, w2.y, w2.z, w2.w, w3.x, w3.y, w3.z, w3.w,
                            w4.x, w4.y, w4.z, w4.w, w5.x, w5.y, w5.z, w5.w};
#pragma unroll
          for (int oc = 0; oc < COUT; ++oc) {
            acc0[oc] += va * wv[oc];
            acc1[oc] += vb * wv[oc];
          }
        }
      }
    }
  }

  int p = (by + ty) * WW + bx + 2 * tx;
  float* ob = out_off + (size_t)b * 18 * HWSZ;
#pragma unroll
  for (int c = 0; c < 16; ++c) {
    int c18 = (c < 8) ? c : c + 2;
    *(float2*)(ob + c18 * HWSZ + p) = make_float2(acc0[c], acc1[c]);
  }
  *(float2*)(ob + 8 * HWSZ + p) = make_float2(0.f, 0.f);
  *(float2*)(ob + 9 * HWSZ + p) = make_float2(0.f, 0.f);
  float* ab = affc + (size_t)b * 8 * HWSZ;
#pragma unroll
  for (int c = 0; c < 8; ++c)
    *(float2*)(ab + c * HWSZ + p) = make_float2(acc0[16 + c], acc1[16 + c]);
}

// ---------------------------------------------------------------------------
// offT3: the c>=4 offset planes (out ch 10..17) as 16 float4 SUBPLANES.
// ---------------------------------------------------------------------------
__global__ __launch_bounds__(256) void offt3_kernel(
    const float* __restrict__ out_off, float4* __restrict__ offT3) {
  __shared__ float lds[64][68];
  int bi = blockIdx.x;
  int vt = bi % 6;  bi /= 6;
  int lt = bi % 6;  bi /= 6;
  int pl = bi % 8;
  int b = bi / 8;
  int cp = pl >> 1, sel = pl & 1;
  const float* src =
      out_off + ((size_t)b * 18 + 10 + pl) * HWSZ + (lt * 64) * WW + vt * 64;
  int t = threadIdx.x;
#pragma unroll
  for (int i = 0; i < 4; ++i) {
    int flat = i * 1024 + t * 4;
    int row = flat >> 6, col = flat & 63;
    *(float4*)&lds[row][col] = *(const float4*)(src + row * WW + col);
  }
  __syncthreads();
#pragma unroll
  for (int i = 0; i < 4; ++i) {
    int f4 = i * 256 + t;
    int Lpl = f4 & 63;
    int ml = (f4 >> 6) & 7;
    int h = f4 >> 9;
    float4 v = *(const float4*)&lds[Lpl][8 * ml + 4 * h];
    int q = sel * 2 + h;
    size_t di = ((size_t)(b * 16 + cp * 4 + q) * 48 + (vt * 8 + ml)) * 384 +
                (lt * 64 + Lpl);
    offT3[di] = v;
  }
}

// ---------------------------------------------------------------------------
// Bilinear sample, zero padding — identical math to the reference (fallback).
// ---------------------------------------------------------------------------
__device__ __forceinline__ float bilin_zero(const float* __restrict__ img,
                                            float iy, float ix) {
  float y0f = floorf(iy), x0f = floorf(ix);
  float wy1 = iy - y0f, wx1 = ix - x0f;
  int y0 = (int)y0f, x0 = (int)x0f;
  float acc = 0.f;
#pragma unroll
  for (int dy = 0; dy < 2; ++dy) {
    int yc = y0 + dy;
    bool vy = (yc >= 0) && (yc <= HH - 1);
    int yi = min(max(yc, 0), HH - 1);
    float wy = dy ? wy1 : 1.f - wy1;
#pragma unroll
    for (int dx = 0; dx < 2; ++dx) {
      int xc = x0 + dx;
      bool vx = (xc >= 0) && (xc <= WW - 1);
      int xi = min(max(xc, 0), WW - 1);
      float wx = dx ? wx1 : 1.f - wx1;
      float v = img[yi * WW + xi];
      acc += v * (wy * wx) * ((vy && vx) ? 1.f : 0.f);
    }
  }
  return acc;
}

// ---------------------------------------------------------------------------
// cw for c=4..7: LDS patch for gathers + cooperative LDS staging of fea
// operands and cw4 results (unchanged from round 19).
// ---------------------------------------------------------------------------
__global__ __launch_bounds__(256, 4) void cw47h_kernel(
    const float* __restrict__ fea, const float4* __restrict__ offT3,
    float* __restrict__ cw4) {
  __shared__ float patch[64][68];   // 17.4 KB
  __shared__ float sfea[8][64][5];  // 10.2 KB
  __shared__ float scw[4][64][5];   //  5.1 KB
  int t = threadIdx.x;
  int lane = t & 63, wv = t >> 6;
  int bi = blockIdx.x;
  int Lblk = bi % 6;  bi /= 6;
  int mblk = bi % 12; bi /= 12;
  int a = bi % 8, b = bi / 8;
  int m = mblk * 4 + wv;

  const float* feab = fea + (size_t)b * 8 * HWSZ;
  const float* imgA = feab + (size_t)a * HWSZ;
  int p_base = a * 18432 + 48 * (Lblk * 64) + mblk * 4;

  int R0 = 32 * mblk - 12;
  R0 = (R0 < 0) ? 0 : (R0 > 320 ? 320 : R0);

#pragma unroll
  for (int i = 0; i < 2; ++i) {
    int L = i * 256 + t;
    int j = L >> 6, Lpl = L & 63;
    float4 v = *(const float4*)(feab + (size_t)j * HWSZ + p_base + 48 * Lpl);
    sfea[j][Lpl][0] = v.x;
    sfea[j][Lpl][1] = v.y;
    sfea[j][Lpl][2] = v.z;
    sfea[j][Lpl][3] = v.w;
  }
  {
    int row = t >> 4, colq = t & 15;
#pragma unroll
    for (int pass = 0; pass < 4; ++pass) {
      int r = pass * 16 + row;
      float4 v = *(const float4*)(imgA + (R0 + r) * WW + R0 + 4 * colq);
      *(float4*)&patch[r][4 * colq] = v;
    }
  }
  __syncthreads();

  float feaj[8];
#pragma unroll
  for (int j = 0; j < 8; ++j) feaj[j] = sfea[j][lane][wv];

  const float4* o3 = offT3 + (size_t)b * 16 * 48 * 384;
  int recoff = m * 384 + (Lblk * 64 + lane);
  float qf = (float)(8 * m);

#pragma unroll
  for (int cp = 0; cp < 4; ++cp) {
    float4 dy0 = o3[(cp * 4 + 0) * 18432 + recoff];
    float4 dy1 = o3[(cp * 4 + 1) * 18432 + recoff];
    float4 dx0 = o3[(cp * 4 + 2) * 18432 + recoff];
    float4 dx1 = o3[(cp * 4 + 3) * 18432 + recoff];
    float dyv[8] = {dy0.x, dy0.y, dy0.z, dy0.w, dy1.x, dy1.y, dy1.z, dy1.w};
    float dxv[8] = {dx0.x, dx0.y, dx0.z, dx0.w, dx1.x, dx1.y, dx1.z, dx1.w};
    float s = 0.f;
#pragma unroll
    for (int j = 0; j < 8; ++j) {
      float iy = dxv[j] + qf + (float)j;
      float ix = dyv[j] + qf + (float)j;
      float y0f = floorf(iy), x0f = floorf(ix);
      int y0 = (int)y0f, x0 = (int)x0f;
      float fy = iy - y0f, fx = ix - x0f;
      float bv;
      if (y0 >= R0 && y0 <= R0 + 62 && x0 >= R0 && x0 <= R0 + 62) {
        int ry = y0 - R0, rx = x0 - R0;
        float v00 = patch[ry][rx], v01 = patch[ry][rx + 1];
        float v10 = patch[ry + 1][rx], v11 = patch[ry + 1][rx + 1];
        float wy0 = 1.f - fy, wx0 = 1.f - fx;
        bv = v00 * (wy0 * wx0) + v01 * (wy0 * fx) + v10 * (fy * wx0) +
             v11 * (fy * fx);
      } else {
        bv = bilin_zero(imgA, iy, ix);
      }
      s += feaj[j] * bv;
    }
    scw[cp][lane][wv] = s;
  }
  __syncthreads();

  {
    int cp = t >> 6, Lpl = t & 63;
    float4 v;
    v.x = scw[cp][Lpl][0];
    v.y = scw[cp][Lpl][1];
    v.z = scw[cp][Lpl][2];
    v.w = scw[cp][Lpl][3];
    *(float4*)(cw4 + (size_t)(b * 4 + cp) * HWSZ + p_base + 48 * Lpl) = v;
  }
}

__device__ __forceinline__ float fast_tanh(float x) {
  float ax = fabsf(x);
  float e = __expf(2.f * ax);  // inf for large ax -> t = 1 (correct limit)
  float t = 1.f - 2.f * __builtin_amdgcn_rcpf(e + 1.f);
  return copysignf(t, x);
}

// ---------------------------------------------------------------------------
// Fused cw03 + epilogue (unchanged from round 19): fpat LDS patch only,
// conf gathers global.
// ---------------------------------------------------------------------------
__global__ __launch_bounds__(256, 4) void fused5_kernel(
    const float* __restrict__ fea, const float* __restrict__ conf_img,
    const float* __restrict__ out_off, const float* __restrict__ affc,
    const float* __restrict__ cw4, const float* __restrict__ aff_scale,
    float* __restrict__ out_aff) {
  __shared__ float fpat[32][36];  // 4.6 KB
  int t = threadIdx.x;
  unsigned idx0 = blockIdx.x * 256u;
  unsigned b = idx0 / (unsigned)HWSZ;
  unsigned pb0 = idx0 % (unsigned)HWSZ;
  unsigned a = (8u * pb0) / (unsigned)HWSZ;
  unsigned r0f = 8u * pb0 - a * (unsigned)HWSZ;
  int hrf = (int)(r0f / (unsigned)WW);
  int C0 = hrf - 12;
  C0 = (C0 < 0) ? 0 : (C0 > 352 ? 352 : C0);
  C0 &= ~3;

  const float* feab = fea + (size_t)b * 8 * HWSZ;
  const float* imgA = feab + (size_t)a * HWSZ;
  const float* cimg = conf_img + (size_t)b * HWSZ;

  unsigned p = pb0 + t;
  const float* offb = out_off + (size_t)b * 18 * HWSZ;
  const float* ab = affc + (size_t)b * 8 * HWSZ;

  float feaj[8];
#pragma unroll
  for (int j = 0; j < 8; ++j) feaj[j] = feab[j * HWSZ + p];
  float abv[8];
#pragma unroll
  for (int c = 0; c < 8; ++c) abv[c] = ab[c * HWSZ + p];
  float cw4v[4];
#pragma unroll
  for (int c = 0; c < 4; ++c) cw4v[c] = cw4[((size_t)b * 4 + c) * HWSZ + p];

  {
    int rr = t >> 3, cq = t & 7;
    *(float4*)&fpat[rr][4 * cq] =
        *(const float4*)(imgA + (C0 + rr) * WW + C0 + 4 * cq);
  }
  __syncthreads();

  unsigned h = p / (unsigned)WW, wcol = p % (unsigned)WW;
  unsigned r0 = 8u * p - a * (unsigned)HWSZ;
  unsigned hr = r0 / (unsigned)WW;
  float cb = (float)hr;

  float av[8];
#pragma unroll
  for (int c = 0; c < 4; ++c) {
    const float* dyp = offb + (2 * c) * HWSZ + r0;
    const float* dxp = offb + (2 * c + 1) * HWSZ + r0;
    float4 dy0 = *(const float4*)dyp, dy1 = *(const float4*)(dyp + 4);
    float4 dx0 = *(const float4*)dxp, dx1 = *(const float4*)(dxp + 4);
    float dyv[8] = {dy0.x, dy0.y, dy0.z, dy0.w, dy1.x, dy1.y, dy1.z, dy1.w};
    float dxv[8] = {dx0.x, dx0.y, dx0.z, dx0.w, dx1.x, dx1.y, dx1.z, dx1.w};
    float s = 0.f;
#pragma unroll
    for (int j = 0; j < 8; ++j) {
      float iy = dxv[j] + cb, ix = dyv[j] + cb;
      float y0f = floorf(iy), x0f = floorf(ix);
      int y0 = (int)y0f, x0 = (int)x0f;
      float fy = iy - y0f, fx = ix - x0f;
      float bv;
      if (y0 >= C0 && y0 <= C0 + 30 && x0 >= C0 && x0 <= C0 + 30) {
        int ry = y0 - C0, rx = x0 - C0;
        float wy0 = 1.f - fy, wx0 = 1.f - fx;
        bv = fpat[ry][rx] * (wy0 * wx0) + fpat[ry][rx + 1] * (wy0 * fx) +
             fpat[ry + 1][rx] * (fy * wx0) + fpat[ry + 1][rx + 1] * (fy * fx);
      } else {
        bv = bilin_zero(imgA, iy, ix);
      }
      s += feaj[j] * bv;
    }
    av[c] = abv[c] * s;
  }
#pragma unroll
  for (int c = 4; c < 8; ++c) av[c] = abv[c] * cw4v[c - 4];

  float cf[8];
#pragma unroll
  for (int c = 0; c < 8; ++c) {
    int chy = (c < 4) ? 2 * c : 2 * c + 2;
    float dy = offb[chy * HWSZ + p];
    float dx = offb[(chy + 1) * HWSZ + p];
    cf[c] = bilin_zero(cimg, dy + (float)h, dx + (float)wcol);
  }

  float invden = __builtin_amdgcn_rcpf(aff_scale[0] + 1e-8f);
  float tv8[8];
  float asum = 0.f;
#pragma unroll
  for (int c = 0; c < 8; ++c) {
    float tv = fast_tanh(av[c]) * invden * cf[c];
    tv8[c] = tv;
    asum += fabsf(tv);
  }
  asum += 1e-4f;
  asum = fmaxf(asum, 1.f);
  float inv_asum = __builtin_amdgcn_rcpf(asum);
  float ssum = 0.f;
#pragma unroll
  for (int c = 0; c < 8; ++c) {
    tv8[c] *= inv_asum;
    ssum += tv8[c];
  }

  float v9[9];
#pragma unroll
  for (int c = 0; c < 4; ++c) v9[c] = tv8[c];
  v9[4] = 1.f - ssum;
#pragma unroll
  for (int c = 4; c < 8; ++c) v9[c + 1] = tv8[c];

  float mx = v9[0];
#pragma unroll
  for (int i = 1; i < 9; ++i) mx = fmaxf(mx, v9[i]);
  float es = 0.f;
#pragma unroll
  for (int i = 0; i < 9; ++i) {
    v9[i] = __expf(v9[i] - mx);
    es += v9[i];
  }
  float inv = __builtin_amdgcn_rcpf(es);
  float* ob = out_aff + (size_t)b * 9 * HWSZ;
#pragma unroll
  for (int i = 0; i < 9; ++i) ob[i * HWSZ + p] = v9[i] * inv;
}

extern "C" void kernel_launch(void* const* d_in, const int* in_sizes, int n_in,
                              void* d_out, int out_size, void* d_ws,
                              size_t ws_size, hipStream_t stream) {
  const float* guidance = (const float*)d_in[0];
  const float* conf_img = (const float*)d_in[1];
  const float* fea = (const float*)d_in[2];
  const float* Wc = (const float*)d_in[3];
  const float* bc = (const float*)d_in[4];
  const float* ascale = (const float*)d_in[5];

  float* out = (float*)d_out;
  float* out_off = out;                           // (4,18,384,384)
  float* out_aff = out + (size_t)Bn * 18 * HWSZ;  // (4,9,384,384) final output
  // offT3 borrows the aff region of d_out; written by offt3, consumed by
  // cw47h before fused5 overwrites the region. 16B-aligned.
  float4* offT3 = (float4*)out_aff;

  float* affc = (float*)d_ws;                     // 4*8*HW floats
  float* cw4 = affc + (size_t)Bn * 8 * HWSZ;      // 4*4*HW floats
  float* Wt = cw4 + (size_t)Bn * 4 * HWSZ;        // 3456 floats

  wtrans_kernel<<<(COUT * CG * 9 + 255) / 256, 256, 0, stream>>>(Wc, Wt);

  int total = Bn * HWSZ;
  conv4_kernel<<<Bn * 24 * 12, 256, 0, stream>>>(guidance, Wt, bc, out_off,
                                                 affc);
  offt3_kernel<<<Bn * 8 * 6 * 6, 256, 0, stream>>>(out_off, offT3);
  cw47h_kernel<<<total / 256, 256, 0, stream>>>(fea, offT3, cw4);
  fused5_kernel<<<total / 256, 256, 0, stream>>>(fea, conf_img, out_off, affc,
                                                 cw4, ascale, out_aff);
}

// Round 21
// 154.042 us; speedup vs baseline: 1.1528x; 1.1528x over previous
//
#include <hip/hip_runtime.h>

constexpr int Bn = 4, CG = 16, HH = 384, WW = 384;
constexpr int HWSZ = HH * WW;  // 147456
constexpr int COUT = 24;
constexpr int TSX = 32, TSY = 16;  // conv tile

// ---------------------------------------------------------------------------
// Weight transpose: Wt[(ic*9+t)*24 + oc] = Wc[(oc*16+ic)*9 + t]
// ---------------------------------------------------------------------------
__global__ void wtrans_kernel(const float* __restrict__ Wc,
                              float* __restrict__ Wt) {
  int i = blockIdx.x * 256 + threadIdx.x;
  if (i < COUT * CG * 9) {
    int oc = i / (CG * 9), rem = i % (CG * 9);
    Wt[rem * COUT + oc] = Wc[i];
  }
}

// ---------------------------------------------------------------------------
// Conv 3x3 SAME 16->24: round-16 structure (best of 5 attempts: 69 us) —
// 32x16 tile, 256 thr, 2 px/thread, 8-ic LDS halves (19.6 KB), s_load
// weights — PLUS the round-14/15 fused offT3 scatter stores (A/B-proven
// free: conv 68-74 us with and without). Replaces the separate ~12 us
// offt3 transpose kernel.
// ---------------------------------------------------------------------------
__global__ __launch_bounds__(256) void conv5_kernel(
    const float* __restrict__ g, const float* __restrict__ Wt,
    const float* __restrict__ bc, float* __restrict__ out_off,
    float* __restrict__ affc, float* __restrict__ offT3f) {
  __shared__ float lds[8 * 18 * 34];  // 19.6 KB
  int bi = blockIdx.x;
  int bx = (bi % (WW / TSX)) * TSX;
  int by = ((bi / (WW / TSX)) % (HH / TSY)) * TSY;
  int b = bi / ((WW / TSX) * (HH / TSY));
  const float* gb = g + (size_t)b * CG * HWSZ;

  int t = threadIdx.x;
  int tx = t & 15, ty = t >> 4;
  float acc0[COUT], acc1[COUT];
#pragma unroll
  for (int oc = 0; oc < COUT; ++oc) {
    float bv = bc[oc];
    acc0[oc] = bv;
    acc1[oc] = bv;
  }

  for (int half = 0; half < 2; ++half) {
    if (half) __syncthreads();
    for (int k = t; k < 8 * 18 * 34; k += 256) {
      int icl = k / 612, rem = k - 612 * icl;
      int y = rem / 34, x = rem - 34 * y;
      int gy = by + y - 1, gx = bx + x - 1;
      float v = (gy >= 0 && gy < HH && gx >= 0 && gx < WW)
                    ? gb[(half * 8 + icl) * HWSZ + gy * WW + gx]
                    : 0.f;
      lds[k] = v;
    }
    __syncthreads();

    for (int icl = 0; icl < 8; ++icl) {
      int ic = half * 8 + icl;
      const float* base = lds + icl * 612 + ty * 34 + 2 * tx;
      float vals[3][4];
#pragma unroll
      for (int r = 0; r < 3; ++r) {
        float2 v01 = *(const float2*)(base + r * 34);
        float2 v23 = *(const float2*)(base + r * 34 + 2);
        vals[r][0] = v01.x;
        vals[r][1] = v01.y;
        vals[r][2] = v23.x;
        vals[r][3] = v23.y;
      }
#pragma unroll
      for (int r = 0; r < 3; ++r) {
#pragma unroll
        for (int c3 = 0; c3 < 3; ++c3) {
          float va = vals[r][c3], vb = vals[r][c3 + 1];
          const float* wp = Wt + (ic * 9 + r * 3 + c3) * COUT;
#pragma unroll
          for (int oc = 0; oc < COUT; ++oc) {
            acc0[oc] += va * wp[oc];
            acc1[oc] += vb * wp[oc];
          }
        }
      }
    }
  }

  int p = (by + ty) * WW + bx + 2 * tx;
  float* ob = out_off + (size_t)b * 18 * HWSZ;
#pragma unroll
  for (int c = 0; c < 16; ++c) {
    int c18 = (c < 8) ? c : c + 2;
    *(float2*)(ob + c18 * HWSZ + p) = make_float2(acc0[c], acc1[c]);
  }
  *(float2*)(ob + 8 * HWSZ + p) = make_float2(0.f, 0.f);
  *(float2*)(ob + 9 * HWSZ + p) = make_float2(0.f, 0.f);
  float* ab = affc + (size_t)b * 8 * HWSZ;
#pragma unroll
  for (int c = 0; c < 8; ++c)
    *(float2*)(ab + c * HWSZ + p) = make_float2(acc0[16 + c], acc1[16 + c]);

  // Fused offT3 subplane stores (replaces offt3_kernel; A/B-proven free).
  {
    int X0 = bx + 2 * tx;
    int m = X0 >> 3, j = X0 & 7;  // j even -> j&3 in {0,2}, float2 ok
    int Lp = by + ty;
    float* o3b = offT3f + (size_t)b * 16 * 48 * 384 * 4;
#pragma unroll
    for (int pl = 0; pl < 8; ++pl) {
      int cp = pl >> 1, sel = pl & 1;
      int q = sel * 2 + (j >> 2);
      size_t di = ((size_t)(cp * 4 + q) * 48 + m) * 384 + Lp;
      *(float2*)(o3b + di * 4 + (j & 3)) =
          make_float2(acc0[8 + pl], acc1[8 + pl]);
    }
  }
}

// ---------------------------------------------------------------------------
// Bilinear sample, zero padding — identical math to the reference (fallback).
// ---------------------------------------------------------------------------
__device__ __forceinline__ float bilin_zero(const float* __restrict__ img,
                                            float iy, float ix) {
  float y0f = floorf(iy), x0f = floorf(ix);
  float wy1 = iy - y0f, wx1 = ix - x0f;
  int y0 = (int)y0f, x0 = (int)x0f;
  float acc = 0.f;
#pragma unroll
  for (int dy = 0; dy < 2; ++dy) {
    int yc = y0 + dy;
    bool vy = (yc >= 0) && (yc <= HH - 1);
    int yi = min(max(yc, 0), HH - 1);
    float wy = dy ? wy1 : 1.f - wy1;
#pragma unroll
    for (int dx = 0; dx < 2; ++dx) {
      int xc = x0 + dx;
      bool vx = (xc >= 0) && (xc <= WW - 1);
      int xi = min(max(xc, 0), WW - 1);
      float wx = dx ? wx1 : 1.f - wx1;
      float v = img[yi * WW + xi];
      acc += v * (wy * wx) * ((vy && vx) ? 1.f : 0.f);
    }
  }
  return acc;
}

// ---------------------------------------------------------------------------
// cw for c=4..7: LDS patch for gathers + cooperative LDS staging of fea
// operands and cw4 results (unchanged from round 19).
// ---------------------------------------------------------------------------
__global__ __launch_bounds__(256, 4) void cw47h_kernel(
    const float* __restrict__ fea, const float4* __restrict__ offT3,
    float* __restrict__ cw4) {
  __shared__ float patch[64][68];   // 17.4 KB
  __shared__ float sfea[8][64][5];  // 10.2 KB
  __shared__ float scw[4][64][5];   //  5.1 KB
  int t = threadIdx.x;
  int lane = t & 63, wv = t >> 6;
  int bi = blockIdx.x;
  int Lblk = bi % 6;  bi /= 6;
  int mblk = bi % 12; bi /= 12;
  int a = bi % 8, b = bi / 8;
  int m = mblk * 4 + wv;

  const float* feab = fea + (size_t)b * 8 * HWSZ;
  const float* imgA = feab + (size_t)a * HWSZ;
  int p_base = a * 18432 + 48 * (Lblk * 64) + mblk * 4;

  int R0 = 32 * mblk - 12;
  R0 = (R0 < 0) ? 0 : (R0 > 320 ? 320 : R0);

#pragma unroll
  for (int i = 0; i < 2; ++i) {
    int L = i * 256 + t;
    int j = L >> 6, Lpl = L & 63;
    float4 v = *(const float4*)(feab + (size_t)j * HWSZ + p_base + 48 * Lpl);
    sfea[j][Lpl][0] = v.x;
    sfea[j][Lpl][1] = v.y;
    sfea[j][Lpl][2] = v.z;
    sfea[j][Lpl][3] = v.w;
  }
  {
    int row = t >> 4, colq = t & 15;
#pragma unroll
    for (int pass = 0; pass < 4; ++pass) {
      int r = pass * 16 + row;
      float4 v = *(const float4*)(imgA + (R0 + r) * WW + R0 + 4 * colq);
      *(float4*)&patch[r][4 * colq] = v;
    }
  }
  __syncthreads();

  float feaj[8];
#pragma unroll
  for (int j = 0; j < 8; ++j) feaj[j] = sfea[j][lane][wv];

  const float4* o3 = offT3 + (size_t)b * 16 * 48 * 384;
  int recoff = m * 384 + (Lblk * 64 + lane);
  float qf = (float)(8 * m);

#pragma unroll
  for (int cp = 0; cp < 4; ++cp) {
    float4 dy0 = o3[(cp * 4 + 0) * 18432 + recoff];
    float4 dy1 = o3[(cp * 4 + 1) * 18432 + recoff];
    float4 dx0 = o3[(cp * 4 + 2) * 18432 + recoff];
    float4 dx1 = o3[(cp * 4 + 3) * 18432 + recoff];
    float dyv[8] = {dy0.x, dy0.y, dy0.z, dy0.w, dy1.x, dy1.y, dy1.z, dy1.w};
    float dxv[8] = {dx0.x, dx0.y, dx0.z, dx0.w, dx1.x, dx1.y, dx1.z, dx1.w};
    float s = 0.f;
#pragma unroll
    for (int j = 0; j < 8; ++j) {
      float iy = dxv[j] + qf + (float)j;
      float ix = dyv[j] + qf + (float)j;
      float y0f = floorf(iy), x0f = floorf(ix);
      int y0 = (int)y0f, x0 = (int)x0f;
      float fy = iy - y0f, fx = ix - x0f;
      float bv;
      if (y0 >= R0 && y0 <= R0 + 62 && x0 >= R0 && x0 <= R0 + 62) {
        int ry = y0 - R0, rx = x0 - R0;
        float v00 = patch[ry][rx], v01 = patch[ry][rx + 1];
        float v10 = patch[ry + 1][rx], v11 = patch[ry + 1][rx + 1];
        float wy0 = 1.f - fy, wx0 = 1.f - fx;
        bv = v00 * (wy0 * wx0) + v01 * (wy0 * fx) + v10 * (fy * wx0) +
             v11 * (fy * fx);
      } else {
        bv = bilin_zero(imgA, iy, ix);
      }
      s += feaj[j] * bv;
    }
    scw[cp][lane][wv] = s;
  }
  __syncthreads();

  {
    int cp = t >> 6, Lpl = t & 63;
    float4 v;
    v.x = scw[cp][Lpl][0];
    v.y = scw[cp][Lpl][1];
    v.z = scw[cp][Lpl][2];
    v.w = scw[cp][Lpl][3];
    *(float4*)(cw4 + (size_t)(b * 4 + cp) * HWSZ + p_base + 48 * Lpl) = v;
  }
}

__device__ __forceinline__ float fast_tanh(float x) {
  float ax = fabsf(x);
  float e = __expf(2.f * ax);  // inf for large ax -> t = 1 (correct limit)
  float t = 1.f - 2.f * __builtin_amdgcn_rcpf(e + 1.f);
  return copysignf(t, x);
}

// ---------------------------------------------------------------------------
// Fused cw03 + epilogue (unchanged from round 19): fpat LDS patch only,
// conf gathers global.
// ---------------------------------------------------------------------------
__global__ __launch_bounds__(256, 4) void fused5_kernel(
    const float* __restrict__ fea, const float* __restrict__ conf_img,
    const float* __restrict__ out_off, const float* __restrict__ affc,
    const float* __restrict__ cw4, const float* __restrict__ aff_scale,
    float* __restrict__ out_aff) {
  __shared__ float fpat[32][36];  // 4.6 KB
  int t = threadIdx.x;
  unsigned idx0 = blockIdx.x * 256u;
  unsigned b = idx0 / (unsigned)HWSZ;
  unsigned pb0 = idx0 % (unsigned)HWSZ;
  unsigned a = (8u * pb0) / (unsigned)HWSZ;
  unsigned r0f = 8u * pb0 - a * (unsigned)HWSZ;
  int hrf = (int)(r0f / (unsigned)WW);
  int C0 = hrf - 12;
  C0 = (C0 < 0) ? 0 : (C0 > 352 ? 352 : C0);
  C0 &= ~3;

  const float* feab = fea + (size_t)b * 8 * HWSZ;
  const float* imgA = feab + (size_t)a * HWSZ;
  const float* cimg = conf_img + (size_t)b * HWSZ;

  unsigned p = pb0 + t;
  const float* offb = out_off + (size_t)b * 18 * HWSZ;
  const float* ab = affc + (size_t)b * 8 * HWSZ;

  float feaj[8];
#pragma unroll
  for (int j = 0; j < 8; ++j) feaj[j] = feab[j * HWSZ + p];
  float abv[8];
#pragma unroll
  for (int c = 0; c < 8; ++c) abv[c] = ab[c * HWSZ + p];
  float cw4v[4];
#pragma unroll
  for (int c = 0; c < 4; ++c) cw4v[c] = cw4[((size_t)b * 4 + c) * HWSZ + p];

  {
    int rr = t >> 3, cq = t & 7;
    *(float4*)&fpat[rr][4 * cq] =
        *(const float4*)(imgA + (C0 + rr) * WW + C0 + 4 * cq);
  }
  __syncthreads();

  unsigned h = p / (unsigned)WW, wcol = p % (unsigned)WW;
  unsigned r0 = 8u * p - a * (unsigned)HWSZ;
  unsigned hr = r0 / (unsigned)WW;
  float cb = (float)hr;

  float av[8];
#pragma unroll
  for (int c = 0; c < 4; ++c) {
    const float* dyp = offb + (2 * c) * HWSZ + r0;
    const float* dxp = offb + (2 * c + 1) * HWSZ + r0;
    float4 dy0 = *(const float4*)dyp, dy1 = *(const float4*)(dyp + 4);
    float4 dx0 = *(const float4*)dxp, dx1 = *(const float4*)(dxp + 4);
    float dyv[8] = {dy0.x, dy0.y, dy0.z, dy0.w, dy1.x, dy1.y, dy1.z, dy1.w};
    float dxv[8] = {dx0.x, dx0.y, dx0.z, dx0.w, dx1.x, dx1.y, dx1.z, dx1.w};
    float s = 0.f;
#pragma unroll
    for (int j = 0; j < 8; ++j) {
      float iy = dxv[j] + cb, ix = dyv[j] + cb;
      float y0f = floorf(iy), x0f = floorf(ix);
      int y0 = (int)y0f, x0 = (int)x0f;
      float fy = iy - y0f, fx = ix - x0f;
      float bv;
      if (y0 >= C0 && y0 <= C0 + 30 && x0 >= C0 && x0 <= C0 + 30) {
        int ry = y0 - C0, rx = x0 - C0;
        float wy0 = 1.f - fy, wx0 = 1.f - fx;
        bv = fpat[ry][rx] * (wy0 * wx0) + fpat[ry][rx + 1] * (wy0 * fx) +
             fpat[ry + 1][rx] * (fy * wx0) + fpat[ry + 1][rx + 1] * (fy * fx);
      } else {
        bv = bilin_zero(imgA, iy, ix);
      }
      s += feaj[j] * bv;
    }
    av[c] = abv[c] * s;
  }
#pragma unroll
  for (int c = 4; c < 8; ++c) av[c] = abv[c] * cw4v[c - 4];

  float cf[8];
#pragma unroll
  for (int c = 0; c < 8; ++c) {
    int chy = (c < 4) ? 2 * c : 2 * c + 2;
    float dy = offb[chy * HWSZ + p];
    float dx = offb[(chy + 1) * HWSZ + p];
    cf[c] = bilin_zero(cimg, dy + (float)h, dx + (float)wcol);
  }

  float invden = __builtin_amdgcn_rcpf(aff_scale[0] + 1e-8f);
  float tv8[8];
  float asum = 0.f;
#pragma unroll
  for (int c = 0; c < 8; ++c) {
    float tv = fast_tanh(av[c]) * invden * cf[c];
    tv8[c] = tv;
    asum += fabsf(tv);
  }
  asum += 1e-4f;
  asum = fmaxf(asum, 1.f);
  float inv_asum = __builtin_amdgcn_rcpf(asum);
  float ssum = 0.f;
#pragma unroll
  for (int c = 0; c < 8; ++c) {
    tv8[c] *= inv_asum;
    ssum += tv8[c];
  }

  float v9[9];
#pragma unroll
  for (int c = 0; c < 4; ++c) v9[c] = tv8[c];
  v9[4] = 1.f - ssum;
#pragma unroll
  for (int c = 4; c < 8; ++c) v9[c + 1] = tv8[c];

  float mx = v9[0];
#pragma unroll
  for (int i = 1; i < 9; ++i) mx = fmaxf(mx, v9[i]);
  float es = 0.f;
#pragma unroll
  for (int i = 0; i < 9; ++i) {
    v9[i] = __expf(v9[i] - mx);
    es += v9[i];
  }
  float inv = __builtin_amdgcn_rcpf(es);
  float* ob = out_aff + (size_t)b * 9 * HWSZ;
#pragma unroll
  for (int i = 0; i < 9; ++i) ob[i * HWSZ + p] = v9[i] * inv;
}

extern "C" void kernel_launch(void* const* d_in, const int* in_sizes, int n_in,
                              void* d_out, int out_size, void* d_ws,
                              size_t ws_size, hipStream_t stream) {
  const float* guidance = (const float*)d_in[0];
  const float* conf_img = (const float*)d_in[1];
  const float* fea = (const float*)d_in[2];
  const float* Wc = (const float*)d_in[3];
  const float* bc = (const float*)d_in[4];
  const float* ascale = (const float*)d_in[5];

  float* out = (float*)d_out;
  float* out_off = out;                           // (4,18,384,384)
  float* out_aff = out + (size_t)Bn * 18 * HWSZ;  // (4,9,384,384) final output
  // offT3 borrows the aff region of d_out; written by conv5, consumed by
  // cw47h before fused5 overwrites the region. 16B-aligned.
  float* offT3f = out_aff;

  float* affc = (float*)d_ws;                     // 4*8*HW floats
  float* cw4 = affc + (size_t)Bn * 8 * HWSZ;      // 4*4*HW floats
  float* Wt = cw4 + (size_t)Bn * 4 * HWSZ;        // 3456 floats

  wtrans_kernel<<<(COUT * CG * 9 + 255) / 256, 256, 0, stream>>>(Wc, Wt);

  int total = Bn * HWSZ;
  conv5_kernel<<<Bn * (HH / TSY) * (WW / TSX), 256, 0, stream>>>(
      guidance, Wt, bc, out_off, affc, offT3f);
  cw47h_kernel<<<total / 256, 256, 0, stream>>>(fea, (const float4*)offT3f,
                                                cw4);
  fused5_kernel<<<total / 256, 256, 0, stream>>>(fea, conf_img, out_off, affc,
                                                 cw4, ascale, out_aff);
}